// Round 1
// baseline (2032.938 us; speedup 1.0000x reference)
//
#include <hip/hip_runtime.h>
#include <math.h>

#define E_EDGES 500000
#define TE 64
#define PI_F 3.14159265358979323846f
#define TWOPI_F 6.28318530717958647692f

// Fused: features + fourier + (65->128 matmul) + LN + relu + (128->128 matmul) + sum over 6 dims.
// Block = 256 threads = 4 waves; tile = 64 edges. Thread (e = tid&63, grp = tid>>6)
// owns a 32-wide slice of the hidden/output dims. Weights read via wave-uniform
// addresses (readfirstlane) -> scalar loads; vector pipe stays pure fmac.
__global__ __launch_bounds__(256, 2)
void rape_fused_kernel(const float* __restrict__ source,
                       const float* __restrict__ target,
                       const int*   __restrict__ edge,
                       const float* __restrict__ freqs,
                       const float* __restrict__ W1,
                       const float* __restrict__ b1,
                       const float* __restrict__ ln_w,
                       const float* __restrict__ ln_b,
                       const float* __restrict__ W2,
                       const float* __restrict__ b2,
                       float* __restrict__ out)
{
    __shared__ float feat_s[6][TE];
    __shared__ float x_s[TE][66];    // 65 + pad; stride 66 -> 2-way bank aliasing (free)
    __shared__ float h_s[TE][130];   // 128 + pad
    __shared__ float red_s[4][TE][2];

    const int tid = threadIdx.x;
    const int e   = tid & 63;
    const int grp = __builtin_amdgcn_readfirstlane(tid >> 6);  // wave-uniform 0..3
    const int eg  = blockIdx.x * TE + e;
    const bool valid = eg < E_EDGES;

    // ---- phase 0: geometric features for the 64-edge tile (wave 0 only) ----
    if (tid < TE) {
        int ec = min(blockIdx.x * TE + tid, E_EDGES - 1);
        int si = edge[ec];
        int ti = edge[E_EDGES + ec];
        const float* S = source + (size_t)si * 5;
        const float* T = target + (size_t)ti * 5;
        float spx = S[0], spy = S[1], shd = S[2], ss = S[3];
        float tpx = T[0], tpy = T[1], thd = T[2], ts = T[3];
        float dx = spx - tpx, dy = spy - tpy;
        float dist = sqrtf(dx * dx + dy * dy);
        float ic  = dist < 3.0f ? 1.0f : 0.0f;
        float inv = dist > 0.0f ? 1.0f / dist : 0.0f;
        float ca  = dist > 0.0f ? dx * inv : 1.0f;   // cos(atan2(dy,dx)), atan2(0,0)=0
        float sa  = dy * inv;                        // 0 when dist==0
        // wrap_angle: ((a+pi) mod 2pi) - pi, python mod semantics (result >= 0)
        float a = shd - thd + PI_F;
        float r = fmodf(a, TWOPI_F);
        r = r < 0.0f ? r + TWOPI_F : r;
        float dh = r - PI_F;
        float tc = ts * (cosf(thd) * ca + sinf(thd) * sa);
        float sc = ss * (cosf(shd) * ca + sinf(shd) * sa);
        feat_s[0][tid] = dx; feat_s[1][tid] = dy; feat_s[2][tid] = dh;
        feat_s[3][tid] = ic; feat_s[4][tid] = tc; feat_s[5][tid] = sc;
    }
    __syncthreads();

    float acc[32];
    #pragma unroll
    for (int i = 0; i < 32; ++i) acc[i] = 0.0f;

    for (int d = 0; d < 6; ++d) {
        const float fv = feat_s[d][e];

        // ---- phase 1: fourier tile. cos(2pi*t) == v_cos_f32(fract(t)) ----
        for (int f = grp; f < 32; f += 4) {
            float fr = freqs[d * 32 + f];          // wave-uniform -> scalar load
            float t  = fv * fr;
            float tf = t - floorf(t);
            x_s[e][f]      = __builtin_amdgcn_cosf(tf);
            x_s[e][f + 32] = __builtin_amdgcn_sinf(tf);
        }
        if (grp == 0) x_s[e][64] = fv;
        __syncthreads();

        // ---- phase 2: h[j] = b1 + sum_k x[k] * W1[d][k][j], j = grp*32..+31 ----
        float h[32];
        {
            const float* bp = b1 + d * 128 + grp * 32;
            #pragma unroll
            for (int j = 0; j < 32; ++j) h[j] = bp[j];
        }
        const float* w1p = W1 + (size_t)d * 65 * 128 + grp * 32;
        for (int k = 0; k < 65; ++k) {
            float xv = x_s[e][k];
            const float* w = w1p + k * 128;        // wave-uniform -> s_load
            #pragma unroll
            for (int j = 0; j < 32; j += 4) {
                float4 wv = *(const float4*)(w + j);
                h[j + 0] = fmaf(xv, wv.x, h[j + 0]);
                h[j + 1] = fmaf(xv, wv.y, h[j + 1]);
                h[j + 2] = fmaf(xv, wv.z, h[j + 2]);
                h[j + 3] = fmaf(xv, wv.w, h[j + 3]);
            }
        }

        // ---- LayerNorm over 128 (4 thread-partials combined via LDS) ----
        float s1 = 0.0f, s2 = 0.0f;
        #pragma unroll
        for (int j = 0; j < 32; ++j) { s1 += h[j]; s2 = fmaf(h[j], h[j], s2); }
        red_s[grp][e][0] = s1; red_s[grp][e][1] = s2;
        __syncthreads();
        float t1 = red_s[0][e][0] + red_s[1][e][0] + red_s[2][e][0] + red_s[3][e][0];
        float t2 = red_s[0][e][1] + red_s[1][e][1] + red_s[2][e][1] + red_s[3][e][1];
        float mu  = t1 * (1.0f / 128.0f);
        float var = t2 * (1.0f / 128.0f) - mu * mu;
        float rinv = rsqrtf(var + 1e-5f);
        {
            const float* lwp = ln_w + d * 128 + grp * 32;
            const float* lbp = ln_b + d * 128 + grp * 32;
            #pragma unroll
            for (int j = 0; j < 32; ++j) {
                float hn = (h[j] - mu) * rinv * lwp[j] + lbp[j];
                h_s[e][grp * 32 + j] = fmaxf(hn, 0.0f);
            }
        }
        __syncthreads();

        // ---- phase 3: acc[g] += b2 + sum_j h[j] * W2[d][j][g], g = grp*32..+31 ----
        {
            const float* bp = b2 + d * 128 + grp * 32;
            #pragma unroll
            for (int g = 0; g < 32; ++g) acc[g] += bp[g];
        }
        const float* w2p = W2 + (size_t)d * 128 * 128 + grp * 32;
        for (int j = 0; j < 128; ++j) {
            float hv = h_s[e][j];
            const float* w = w2p + j * 128;        // wave-uniform -> s_load
            #pragma unroll
            for (int g = 0; g < 32; g += 4) {
                float4 wv = *(const float4*)(w + g);
                acc[g + 0] = fmaf(hv, wv.x, acc[g + 0]);
                acc[g + 1] = fmaf(hv, wv.y, acc[g + 1]);
                acc[g + 2] = fmaf(hv, wv.z, acc[g + 2]);
                acc[g + 3] = fmaf(hv, wv.w, acc[g + 3]);
            }
        }
        __syncthreads();  // protect x_s/h_s/red_s for next d
    }

    // ---- store: 128 floats per edge, this thread's 32-wide slice ----
    if (valid) {
        float* op = out + (size_t)eg * 128 + grp * 32;
        #pragma unroll
        for (int g = 0; g < 32; g += 4) {
            float4 v; v.x = acc[g]; v.y = acc[g + 1]; v.z = acc[g + 2]; v.w = acc[g + 3];
            *(float4*)(op + g) = v;
        }
    }
}

extern "C" void kernel_launch(void* const* d_in, const int* in_sizes, int n_in,
                              void* d_out, int out_size, void* d_ws, size_t ws_size,
                              hipStream_t stream) {
    const float* source = (const float*)d_in[0];
    const float* target = (const float*)d_in[1];
    const int*   edge   = (const int*)  d_in[2];
    const float* freqs  = (const float*)d_in[3];
    const float* W1     = (const float*)d_in[4];
    const float* b1     = (const float*)d_in[5];
    const float* ln_w   = (const float*)d_in[6];
    const float* ln_b   = (const float*)d_in[7];
    const float* W2     = (const float*)d_in[8];
    const float* b2     = (const float*)d_in[9];
    float* out = (float*)d_out;

    const int nblocks = (E_EDGES + TE - 1) / TE;  // 7813
    rape_fused_kernel<<<nblocks, 256, 0, stream>>>(
        source, target, edge, freqs, W1, b1, ln_w, ln_b, W2, b2, out);
}

// Round 2
// 284.863 us; speedup vs baseline: 7.1365x; 7.1365x over previous
//
#include <hip/hip_runtime.h>
#include <hip/hip_bf16.h>
#include <math.h>

#define E_EDGES 500000
#define PI_F 3.14159265358979323846f
#define TWOPI_F 6.28318530717958647692f

typedef __attribute__((ext_vector_type(4))) float f32x4;
typedef __attribute__((ext_vector_type(8))) short s16x8;

static __device__ __forceinline__ short f2bf(float x) {
    __hip_bfloat16 h = __float2bfloat16(x);
    return __builtin_bit_cast(short, h);
}

// Fully-fused MFMA version. Block = 256 thr = 4 waves, 128 edges (32/wave).
// Both matmuls computed transposed: D1'[j][e] = W1^T x^T, D2'[g'][e] = W2^T H'.
// m1 B-operand (fourier) built in registers from trig; m1 output fragment layout
// == m2 B-operand fragment layout, so LN+ReLU stay entirely in registers.
// Weights staged per-d into LDS in fragment-slot layout (one b128 per A-frag).
__global__ __launch_bounds__(256, 2)
void rape_mfma_kernel(const float* __restrict__ source,
                      const float* __restrict__ target,
                      const int*   __restrict__ edge,
                      const float* __restrict__ freqs,
                      const float* __restrict__ W1,
                      const float* __restrict__ b1,
                      const float* __restrict__ ln_w,
                      const float* __restrict__ ln_b,
                      const float* __restrict__ W2,
                      const float* __restrict__ b2,
                      float* __restrict__ out)
{
    // W1T slots: [(ks*4+g)][j], ks=0..2 (ks2: k=64 one-hot, g>0 slots all-zero)
    __shared__ s16x8 w1t[12 * 128];
    // W2T slots: [(ks*4+g)][g'], ks=0..3
    __shared__ s16x8 w2t[16 * 128];
    __shared__ float feat_s[6][128];
    __shared__ float freq_s[6 * 32];
    __shared__ float b1_s[6 * 128];
    __shared__ float lnw_s[6 * 128];
    __shared__ float lnb_s[6 * 128];

    const int tid   = threadIdx.x;
    const int lane  = tid & 63;
    const int wv    = tid >> 6;      // wave 0..3
    const int c     = lane & 15;     // col-in-tile (edge within 16)
    const int g     = lane >> 4;     // k-group 0..3
    const int half  = tid >> 7;      // staging split
    const int ebase = blockIdx.x * 128;

    // ---- pre-loop staging: features (threads 0..127), freqs, b1/ln params ----
    if (tid < 128) {
        int ec = ebase + tid; if (ec >= E_EDGES) ec = E_EDGES - 1;
        int si = edge[ec];
        int ti = edge[E_EDGES + ec];
        const float* S = source + (size_t)si * 5;
        const float* T = target + (size_t)ti * 5;
        float spx = S[0], spy = S[1], shd = S[2], ss = S[3];
        float tpx = T[0], tpy = T[1], thd = T[2], ts = T[3];
        float dx = spx - tpx, dy = spy - tpy;
        float dist = sqrtf(dx * dx + dy * dy);
        float ic  = dist < 3.0f ? 1.0f : 0.0f;
        float inv = dist > 0.0f ? 1.0f / dist : 0.0f;
        float ca  = dist > 0.0f ? dx * inv : 1.0f;   // cos(atan2), atan2(0,0)=0
        float sa  = dy * inv;
        float a = shd - thd + PI_F;
        float r = fmodf(a, TWOPI_F);
        r = r < 0.0f ? r + TWOPI_F : r;
        float dh = r - PI_F;
        float tc = ts * (cosf(thd) * ca + sinf(thd) * sa);
        float sc = ss * (cosf(shd) * ca + sinf(shd) * sa);
        feat_s[0][tid] = dx; feat_s[1][tid] = dy; feat_s[2][tid] = dh;
        feat_s[3][tid] = ic; feat_s[4][tid] = tc; feat_s[5][tid] = sc;
    }
    if (tid < 192) freq_s[tid] = freqs[tid];
    for (int i = tid; i < 768; i += 256) {
        b1_s[i] = b1[i]; lnw_s[i] = ln_w[i]; lnb_s[i] = ln_b[i];
    }
    {
        s16x8 z = {0, 0, 0, 0, 0, 0, 0, 0};
        for (int i = tid; i < 3 * 128; i += 256) w1t[9 * 128 + i] = z;  // ks2,g=1..3
    }

    // ---- acc init: sum_d b2[d][g'],  g' = 4g + r + 16gt ----
    f32x4 acc[2][8];
    #pragma unroll
    for (int gt = 0; gt < 8; ++gt) {
        f32x4 s = {0.f, 0.f, 0.f, 0.f};
        #pragma unroll
        for (int d = 0; d < 6; ++d) {
            const f32x4 v = *(const f32x4*)(b2 + d * 128 + gt * 16 + g * 4);
            s += v;
        }
        acc[0][gt] = s; acc[1][gt] = s;
    }

    for (int d = 0; d < 6; ++d) {
        __syncthreads();  // previous-d fragment reads complete before overwrite

        // ---- stage W1T: slot (ks,g2,j) holds W1[32ks+4g2+{0..3,16..19}][j] as bf16
        {
            const int j = tid & 127;
            const float* W1d = W1 + (size_t)d * 65 * 128;
            #pragma unroll
            for (int it = 0; it < 4; ++it) {
                const int sg = half + it * 2;              // 0..7 (ks 0..1)
                const int kb = (sg >> 2) * 32 + (sg & 3) * 4;
                s16x8 v;
                #pragma unroll
                for (int i = 0; i < 4; ++i) {
                    v[i]     = f2bf(W1d[(kb + i) * 128 + j]);
                    v[i + 4] = f2bf(W1d[(kb + 16 + i) * 128 + j]);
                }
                w1t[sg * 128 + j] = v;
            }
            if (half == 0) {                               // ks=2, g2=0: k=64 one-hot
                s16x8 v = {0, 0, 0, 0, 0, 0, 0, 0};
                v[0] = f2bf(W1d[64 * 128 + j]);
                w1t[8 * 128 + j] = v;
            }
            const float* W2d = W2 + (size_t)d * 128 * 128;
            #pragma unroll
            for (int it = 0; it < 8; ++it) {
                const int sg = half + it * 2;              // 0..15
                const int kb = (sg >> 2) * 32 + (sg & 3) * 4;
                s16x8 v;
                #pragma unroll
                for (int i = 0; i < 4; ++i) {
                    v[i]     = f2bf(W2d[(kb + i) * 128 + j]);
                    v[i + 4] = f2bf(W2d[(kb + 16 + i) * 128 + j]);
                }
                w2t[sg * 128 + j] = v;
            }
        }
        __syncthreads();

        // ---- m1 B-frags from trig (in registers). k = 32ks + 4g + q + 16p ----
        s16x8 bfr[2][3];
        #pragma unroll
        for (int es = 0; es < 2; ++es) {
            const float x = feat_s[d][wv * 32 + es * 16 + c];
            const f32x4 fq0 = *(const f32x4*)(freq_s + d * 32 + g * 4);        // p=0
            const f32x4 fq1 = *(const f32x4*)(freq_s + d * 32 + 16 + g * 4);   // p=1
            s16x8 bc, bs;
            #pragma unroll
            for (int i = 0; i < 8; ++i) {
                const float f = (i < 4) ? fq0[i] : fq1[i - 4];
                const float t = x * f;
                const float tf = t - floorf(t);
                bc[i] = f2bf(__builtin_amdgcn_cosf(tf));   // cos(2*pi*t)
                bs[i] = f2bf(__builtin_amdgcn_sinf(tf));
            }
            s16x8 bx = {0, 0, 0, 0, 0, 0, 0, 0};
            if (g == 0) bx[0] = f2bf(x);                   // k==64 passthrough
            bfr[es][0] = bc; bfr[es][1] = bs; bfr[es][2] = bx;
        }

        // ---- m1: D1'[j][e] = sum_k W1^T[j][k] * X^T[k][e]  (+ b1 init) ----
        f32x4 d1[2][8];
        #pragma unroll
        for (int jt = 0; jt < 8; ++jt) {
            const f32x4 bv = *(const f32x4*)(b1_s + d * 128 + jt * 16 + g * 4);
            d1[0][jt] = bv; d1[1][jt] = bv;
        }
        #pragma unroll
        for (int jt = 0; jt < 8; ++jt) {
            const s16x8 a0 = w1t[(0 + g) * 128 + jt * 16 + c];
            const s16x8 a1 = w1t[(4 + g) * 128 + jt * 16 + c];
            const s16x8 a2 = w1t[(8 + g) * 128 + jt * 16 + c];
            #pragma unroll
            for (int es = 0; es < 2; ++es) {
                d1[es][jt] = __builtin_amdgcn_mfma_f32_16x16x32_bf16(a0, bfr[es][0], d1[es][jt], 0, 0, 0);
                d1[es][jt] = __builtin_amdgcn_mfma_f32_16x16x32_bf16(a1, bfr[es][1], d1[es][jt], 0, 0, 0);
                d1[es][jt] = __builtin_amdgcn_mfma_f32_16x16x32_bf16(a2, bfr[es][2], d1[es][jt], 0, 0, 0);
            }
        }

        // ---- LayerNorm over j (in registers; lane holds j = 4g+q+16jt) ----
        // stats reduce across the 4 lanes {c, c+16, c+32, c+48}
        s16x8 pb[2][4];
        #pragma unroll
        for (int es = 0; es < 2; ++es) {
            float s1 = 0.f, s2 = 0.f;
            #pragma unroll
            for (int jt = 0; jt < 8; ++jt)
                #pragma unroll
                for (int q = 0; q < 4; ++q) {
                    const float v = d1[es][jt][q];
                    s1 += v; s2 = fmaf(v, v, s2);
                }
            s1 += __shfl_xor(s1, 16); s1 += __shfl_xor(s1, 32);
            s2 += __shfl_xor(s2, 16); s2 += __shfl_xor(s2, 32);
            const float mu   = s1 * 0.0078125f;
            const float var  = s2 * 0.0078125f - mu * mu;
            const float rinv = rsqrtf(var + 1e-5f);
            #pragma unroll
            for (int ks = 0; ks < 4; ++ks) {
                #pragma unroll
                for (int p = 0; p < 2; ++p) {
                    const int jt = 2 * ks + p;
                    const f32x4 lw = *(const f32x4*)(lnw_s + d * 128 + jt * 16 + g * 4);
                    const f32x4 lb = *(const f32x4*)(lnb_s + d * 128 + jt * 16 + g * 4);
                    #pragma unroll
                    for (int q = 0; q < 4; ++q) {
                        float hv = (d1[es][jt][q] - mu) * rinv;
                        hv = fmaf(hv, lw[q], lb[q]);
                        hv = fmaxf(hv, 0.f);
                        pb[es][ks][q + 4 * p] = f2bf(hv);   // m2 B-frag, k=j
                    }
                }
            }
        }

        // ---- m2: acc[g'][e] += sum_j W2^T[g'][j] * H'[j][e] ----
        #pragma unroll
        for (int gt = 0; gt < 8; ++gt) {
            const s16x8 a0 = w2t[(0 * 4 + g) * 128 + gt * 16 + c];
            const s16x8 a1 = w2t[(1 * 4 + g) * 128 + gt * 16 + c];
            const s16x8 a2 = w2t[(2 * 4 + g) * 128 + gt * 16 + c];
            const s16x8 a3 = w2t[(3 * 4 + g) * 128 + gt * 16 + c];
            #pragma unroll
            for (int es = 0; es < 2; ++es) {
                acc[es][gt] = __builtin_amdgcn_mfma_f32_16x16x32_bf16(a0, pb[es][0], acc[es][gt], 0, 0, 0);
                acc[es][gt] = __builtin_amdgcn_mfma_f32_16x16x32_bf16(a1, pb[es][1], acc[es][gt], 0, 0, 0);
                acc[es][gt] = __builtin_amdgcn_mfma_f32_16x16x32_bf16(a2, pb[es][2], acc[es][gt], 0, 0, 0);
                acc[es][gt] = __builtin_amdgcn_mfma_f32_16x16x32_bf16(a3, pb[es][3], acc[es][gt], 0, 0, 0);
            }
        }
    }

    // ---- store: lane holds cols g' = 4g + r + 16gt of edges (wv*32 + es*16 + c)
    #pragma unroll
    for (int es = 0; es < 2; ++es) {
        const int e = ebase + wv * 32 + es * 16 + c;
        if (e < E_EDGES) {
            float* op = out + (size_t)e * 128 + g * 4;
            #pragma unroll
            for (int gt = 0; gt < 8; ++gt)
                *(f32x4*)(op + gt * 16) = acc[es][gt];
        }
    }
}

extern "C" void kernel_launch(void* const* d_in, const int* in_sizes, int n_in,
                              void* d_out, int out_size, void* d_ws, size_t ws_size,
                              hipStream_t stream) {
    const float* source = (const float*)d_in[0];
    const float* target = (const float*)d_in[1];
    const int*   edge   = (const int*)  d_in[2];
    const float* freqs  = (const float*)d_in[3];
    const float* W1     = (const float*)d_in[4];
    const float* b1     = (const float*)d_in[5];
    const float* ln_w   = (const float*)d_in[6];
    const float* ln_b   = (const float*)d_in[7];
    const float* W2     = (const float*)d_in[8];
    const float* b2     = (const float*)d_in[9];
    float* out = (float*)d_out;

    const int nblocks = (E_EDGES + 127) / 128;  // 3907
    rape_mfma_kernel<<<nblocks, 256, 0, stream>>>(
        source, target, edge, freqs, W1, b1, ln_w, ln_b, W2, b2, out);
}